// Round 9
// baseline (219.856 us; speedup 1.0000x reference)
//
#include <hip/hip_runtime.h>
#include <hip/hip_bf16.h>
#include <stdint.h>

// Problem constants
#define B_ 32
#define N_ 4096
#define M_ 256
#define L_ 128
#define H_ 4
#define BN_ (B_ * N_)          // 131072 flattened rows

typedef __bf16 bf16x8 __attribute__((ext_vector_type(8)));
typedef float  f32x4  __attribute__((ext_vector_type(4)));

__device__ __forceinline__ unsigned short f2bf(float f) {
    // round-to-nearest-even f32 -> bf16
    unsigned int u = __float_as_uint(f);
    u += 0x7fffu + ((u >> 16) & 1u);
    return (unsigned short)(u >> 16);
}
__device__ __forceinline__ unsigned int pack2(float lo, float hi) {
    return (unsigned int)f2bf(lo) | ((unsigned int)f2bf(hi) << 16);
}

// async global->LDS, 16B per lane. LDS dest is wave-uniform base (+lane*16 by HW);
// global src is per-lane.
__device__ __forceinline__ void gload16(const void* g, void* l) {
    __builtin_amdgcn_global_load_lds(
        (const __attribute__((address_space(1))) unsigned int*)g,
        (__attribute__((address_space(3))) unsigned int*)l, 16, 0, 0);
}

// Image geometry: each K-step image is [128 rows][32 k] bf16 = 8192 B,
// row stride 64 B. Swizzle: byte ^= (row&14)<<3 (bits 4..6 <- row bits 1..3).
// 16-lane fragment reads: 0 measured conflicts (rounds 7/8).

// ---------------------------------------------------------------------------
// prep: V,U (H,M,L) f32 -> vu images [(h*8 + s)*2 + mat][128 l][32 m] bf16,
// swizzled, PRESCALED: V *= 2 (tanh doubling), U *= -1 (sigmoid negate) so the
// GEMM epilogue is A=exp(accV)=e^{2v}, E=exp(accU)=e^{-u} with no extra muls.
// ---------------------------------------------------------------------------
__global__ void prep_vu_img(const float* __restrict__ V, const float* __restrict__ U,
                            unsigned short* __restrict__ vu) {
    __shared__ float slab[64][129];     // [m][l], padded
    const int b   = blockIdx.x;         // 32 = h(4) * ks64(4) * mat(2)
    const int mat = b & 1, ks = (b >> 1) & 3, h = b >> 3;
    const float* src = (mat ? U : V) + ((size_t)h * M_ + ks * 64) * L_;
    const float scale = mat ? -1.0f : 2.0f;
    const int tid = threadIdx.x;
#pragma unroll
    for (int rep = 0; rep < 32; ++rep) {
        int idx = rep * 256 + tid;      // 8192 = 64m x 128l
        slab[idx >> 7][idx & 127] = scale * src[(size_t)(idx >> 7) * L_ + (idx & 127)];
    }
    __syncthreads();
#pragma unroll
    for (int rep = 0; rep < 4; ++rep) {
        int cidx = rep * 256 + tid;     // 1024 chunks of 16B (two 8KB images)
        int l  = cidx >> 3;             // 0..127
        int kk = (cidx & 7) * 8;        // 0..56
        uint4 o;
        o.x = pack2(slab[kk + 0][l], slab[kk + 1][l]);
        o.y = pack2(slab[kk + 2][l], slab[kk + 3][l]);
        o.z = pack2(slab[kk + 4][l], slab[kk + 5][l]);
        o.w = pack2(slab[kk + 6][l], slab[kk + 7][l]);
        int tl = kk >> 5, kl = kk & 31;
        char* dst = (char*)vu + (((size_t)(h * 8 + ks * 2 + tl)) * 2 + mat) * 8192;
        int byte = (l * 64 + kl * 2) ^ ((l & 14) << 3);
        *(uint4*)(dst + byte) = o;
    }
}

// ---------------------------------------------------------------------------
// gemm_fast7: inline x staging (no prep_x / no xb HBM round-trip).
// logits[b,h,n] = sum_l tanh(xV)*sigmoid(xU)*w[h,l]
// Per step t: [vmcnt(0): B(t) landed][barrier]
//             [issue x-loads(t+1) f32->regs  (FIRST: oldest in vmcnt order)]
//             [issue B-stage(t+1) gload16]
//             [ds_read + 32 MFMA on buf t]
//             [cvt x(t+1) (auto vmcnt(4) drains x, keeps B in flight)
//              + 2 swizzled ds_write_b128 -> xs[t+1]]
//             [lgkmcnt(0)]  -> next barrier.
// x f32 read straight from HBM/L2 (h-inner XCD swizzle: 1x HBM + 3x L2).
// 64x64 wave tiles, (row&14)<<3 swizzle, 2-buffer 48KB LDS, 3 blocks/CU.
// ---------------------------------------------------------------------------
__global__ __launch_bounds__(256, 3)
void gemm_fast7(const float* __restrict__ x,
                const unsigned short* __restrict__ vu,
                const float* __restrict__ w,
                float* __restrict__ logits) {
    __shared__ __align__(16) unsigned short xs[2][4096];   // 2 x 8KB
    __shared__ __align__(16) unsigned short vs[2][4096];
    __shared__ __align__(16) unsigned short us[2][4096];
    __shared__ float part[2][128];

    const int orig    = blockIdx.x;                 // 4096, %8==0 -> bijective
    const int logical = (orig & 7) * 512 + (orig >> 3);
    const int tile    = logical >> 2;
    const int h       = logical & 3;

    const int tid  = threadIdx.x;
    const int lane = tid & 63;
    const int wv   = tid >> 6;
    const int g    = lane >> 4;     // k-group 0..3
    const int c    = lane & 15;     // row (A) / col (B) within fragment
    const int wr   = wv & 1;        // wave row half
    const int wc   = wv >> 1;       // wave l half

    f32x4 accV[4][4], accU[4][4];
#pragma unroll
    for (int rf = 0; rf < 4; ++rf)
#pragma unroll
        for (int cf = 0; cf < 4; ++cf) {
            accV[rf][cf] = (f32x4){0.f, 0.f, 0.f, 0.f};
            accU[rf][cf] = (f32x4){0.f, 0.f, 0.f, 0.f};
        }

    const int soff = wv * 2048;     // this wave's quarter of each 8KB image

    // B global sources (pre-swizzled images; step stride 16384 B)
    const char* gvs = (const char*)vu + (size_t)h * 131072 + soff + lane * 16;
    const char* gus = gvs + 8192;

    // x source: lane handles 16 consecutive f32 (64 B) of one row per step.
    const int rL   = lane >> 1;     // 0..31 within the wave's 32-row stripe
    const int half = lane & 1;      // which 16-float half of the 32-k chunk
    const float* gx = x + ((size_t)tile * 128 + wv * 32 + rL) * M_ + half * 16;

    // x LDS write offsets (swizzled); second 16B slot is b0^16 (bit4 in XOR span)
    const int xrow = wv * 32 + rL;
    const int xb0  = (xrow * 64 + half * 32) ^ ((xrow & 14) << 3);

    // hoisted swizzled LDS read byte offsets
    int aoff[4], boff[4];
#pragma unroll
    for (int rf = 0; rf < 4; ++rf) {
        int r = wr * 64 + rf * 16 + c;
        aoff[rf] = (r * 64 + g * 16) ^ ((r & 14) << 3);
    }
#pragma unroll
    for (int cf = 0; cf < 4; ++cf) {
        int l = wc * 64 + cf * 16 + c;
        boff[cf] = (l * 64 + g * 16) ^ ((l & 14) << 3);
    }

    float4 xr0, xr1, xr2, xr3;      // in-flight x (16 f32)

#define SCHED __builtin_amdgcn_sched_barrier(0)

#define LOADX(t) do {                                                \
        xr0 = *(const float4*)(gx + (t) * 32);                       \
        xr1 = *(const float4*)(gx + (t) * 32 + 4);                   \
        xr2 = *(const float4*)(gx + (t) * 32 + 8);                   \
        xr3 = *(const float4*)(gx + (t) * 32 + 12);                  \
    } while (0)

#define WRITEX(bufi) do {                                            \
        bf16x8 lo, hi;                                               \
        lo[0] = (__bf16)xr0.x; lo[1] = (__bf16)xr0.y;                \
        lo[2] = (__bf16)xr0.z; lo[3] = (__bf16)xr0.w;                \
        lo[4] = (__bf16)xr1.x; lo[5] = (__bf16)xr1.y;                \
        lo[6] = (__bf16)xr1.z; lo[7] = (__bf16)xr1.w;                \
        hi[0] = (__bf16)xr2.x; hi[1] = (__bf16)xr2.y;                \
        hi[2] = (__bf16)xr2.z; hi[3] = (__bf16)xr2.w;                \
        hi[4] = (__bf16)xr3.x; hi[5] = (__bf16)xr3.y;                \
        hi[6] = (__bf16)xr3.z; hi[7] = (__bf16)xr3.w;                \
        *(bf16x8*)((char*)xs[bufi] + xb0)        = lo;               \
        *(bf16x8*)((char*)xs[bufi] + (xb0 ^ 16)) = hi;               \
    } while (0)

#define STAGEB(t, bufi) do {                                         \
        const char* _gv = gvs + (t) * 16384;                         \
        const char* _gu = gus + (t) * 16384;                         \
        gload16(_gv,        (char*)vs[bufi] + soff);                 \
        gload16(_gv + 1024, (char*)vs[bufi] + soff + 1024);          \
        gload16(_gu,        (char*)us[bufi] + soff);                 \
        gload16(_gu + 1024, (char*)us[bufi] + soff + 1024);          \
    } while (0)

    // prologue: x(0) -> regs -> xs[0]; stage B(0)
    LOADX(0);
    SCHED;
    STAGEB(0, 0);
    SCHED;
    WRITEX(0);                      // compiler waits x-loads (B stays in flight)
    asm volatile("s_waitcnt lgkmcnt(0)" ::: "memory");
    SCHED;

#pragma unroll
    for (int t = 0; t < 8; ++t) {
        asm volatile("s_waitcnt vmcnt(0)" ::: "memory");  // B(t) landed
        __builtin_amdgcn_s_barrier();
        SCHED;

        if (t < 7) {
            LOADX(t + 1);           // issue x FIRST (oldest -> drained by vmcnt(4))
            SCHED;
            STAGEB(t + 1, (t + 1) & 1);
            SCHED;
        }

        const int buf = t & 1;      // compile-time after unroll
        const char* xbuf = (const char*)xs[buf];
        const char* vbuf = (const char*)vs[buf];
        const char* ubuf = (const char*)us[buf];

        bf16x8 a0 = *(const bf16x8*)(xbuf + aoff[0]);
        bf16x8 a1 = *(const bf16x8*)(xbuf + aoff[1]);
        bf16x8 a2 = *(const bf16x8*)(xbuf + aoff[2]);
        bf16x8 a3 = *(const bf16x8*)(xbuf + aoff[3]);
        __builtin_amdgcn_s_setprio(1);
#pragma unroll
        for (int cf = 0; cf < 4; ++cf) {
            bf16x8 bv = *(const bf16x8*)(vbuf + boff[cf]);
            bf16x8 bu = *(const bf16x8*)(ubuf + boff[cf]);
            accV[0][cf] = __builtin_amdgcn_mfma_f32_16x16x32_bf16(a0, bv, accV[0][cf], 0, 0, 0);
            accV[1][cf] = __builtin_amdgcn_mfma_f32_16x16x32_bf16(a1, bv, accV[1][cf], 0, 0, 0);
            accV[2][cf] = __builtin_amdgcn_mfma_f32_16x16x32_bf16(a2, bv, accV[2][cf], 0, 0, 0);
            accV[3][cf] = __builtin_amdgcn_mfma_f32_16x16x32_bf16(a3, bv, accV[3][cf], 0, 0, 0);
            accU[0][cf] = __builtin_amdgcn_mfma_f32_16x16x32_bf16(a0, bu, accU[0][cf], 0, 0, 0);
            accU[1][cf] = __builtin_amdgcn_mfma_f32_16x16x32_bf16(a1, bu, accU[1][cf], 0, 0, 0);
            accU[2][cf] = __builtin_amdgcn_mfma_f32_16x16x32_bf16(a2, bu, accU[2][cf], 0, 0, 0);
            accU[3][cf] = __builtin_amdgcn_mfma_f32_16x16x32_bf16(a3, bu, accU[3][cf], 0, 0, 0);
        }
        __builtin_amdgcn_s_setprio(0);
        SCHED;

        if (t < 7) {
            WRITEX((t + 1) & 1);    // auto vmcnt(4): x(t+1) done, B(t+1) in flight
        }
        asm volatile("s_waitcnt lgkmcnt(0)" ::: "memory");
        SCHED;
    }
#undef STAGEB
#undef WRITEX
#undef LOADX
#undef SCHED

    // ---- epilogue: V prescaled by 2, U by -1 -> A=e^{2v}, E=e^{-u}.
    //      gated = (A-1)/((A+1)(1+E)); dot w over wave's 64 l; 16-lane reduce;
    //      join l-halves via LDS part[]. No clamps: |acc| << 88 (inputs ~N(0,1),
    //      weights 0.02-scale -> |acc| <~ 6).
    const float* wrow = w + h * L_ + wc * 64;
#pragma unroll
    for (int rf = 0; rf < 4; ++rf) {
        float plog[4] = {0.f, 0.f, 0.f, 0.f};
#pragma unroll
        for (int cf = 0; cf < 4; ++cf) {
            float wvv = wrow[cf * 16 + c];
#pragma unroll
            for (int i = 0; i < 4; ++i) {
                float A = __expf(accV[rf][cf][i]);
                float E = __expf(accU[rf][cf][i]);
                float gg = __fdividef(A - 1.f, (A + 1.f) * (1.f + E));
                plog[i] += gg * wvv;
            }
        }
#pragma unroll
        for (int i = 0; i < 4; ++i) {
            float v = plog[i];
            v += __shfl_xor(v, 1);
            v += __shfl_xor(v, 2);
            v += __shfl_xor(v, 4);
            v += __shfl_xor(v, 8);      // sum over the 16 col-lanes
            if (c == 0)
                part[wc][wr * 64 + rf * 16 + g * 4 + i] = v;
        }
    }
    __syncthreads();
    if (tid < 128) {
        float v = part[0][tid] + part[1][tid];
        int rowflat = tile * 128 + tid;
        int b = rowflat >> 12;           // / N_
        int n = rowflat & (N_ - 1);
        logits[((size_t)b * H_ + h) * N_ + n] = v;
    }
}

// ---------------------------------------------------------------------------
// SLOW PATH (round-1 fallback, used only if ws_size is too small)
// ---------------------------------------------------------------------------
__global__ void prep_vu_slow(const float* __restrict__ V, const float* __restrict__ U,
                             unsigned short* __restrict__ Vt, unsigned short* __restrict__ Ut) {
    int idx = blockIdx.x * 256 + threadIdx.x;
    int m = idx & (M_ - 1);
    int l = (idx >> 8) & (L_ - 1);
    int h = idx >> 15;
    Vt[idx] = f2bf(V[((size_t)h * M_ + m) * L_ + l]);
    Ut[idx] = f2bf(U[((size_t)h * M_ + m) * L_ + l]);
}

#define BM 128
#define BK 64

__global__ __launch_bounds__(256, 2)
void gemm_logits(const float* __restrict__ x,
                 const unsigned short* __restrict__ Vt,
                 const unsigned short* __restrict__ Ut,
                 const float* __restrict__ w,
                 float* __restrict__ logits) {
    __shared__ __align__(16) unsigned short xs[BM * BK];
    __shared__ __align__(16) unsigned short vs[L_ * BK];
    __shared__ __align__(16) unsigned short us[L_ * BK];
    __shared__ float wl[L_];

    const int h    = blockIdx.x >> 10;
    const int tile = blockIdx.x & 1023;
    const int row0 = tile * BM;
    const int tid  = threadIdx.x;
    const int lane = tid & 63;
    const int wave = tid >> 6;

    if (tid < L_) wl[tid] = w[h * L_ + tid];

    f32x4 accV[2][8], accU[2][8];
#pragma unroll
    for (int rf = 0; rf < 2; ++rf)
#pragma unroll
        for (int cf = 0; cf < 8; ++cf) {
            accV[rf][cf] = (f32x4){0.f, 0.f, 0.f, 0.f};
            accU[rf][cf] = (f32x4){0.f, 0.f, 0.f, 0.f};
        }

    const unsigned short* Vh = Vt + (size_t)h * L_ * M_;
    const unsigned short* Uh = Ut + (size_t)h * L_ * M_;
    const int g = lane >> 4;
    const int c = lane & 15;

    for (int ks = 0; ks < 4; ++ks) {
        const int k0 = ks * BK;
        __syncthreads();
#pragma unroll
        for (int p = 0; p < 4; ++p) {
            int row = p * 32 + (tid >> 3);
            int kk  = (tid & 7) * 8;
            const float* gx = x + (size_t)(row0 + row) * M_ + k0 + kk;
            float4 a = *(const float4*)gx;
            float4 b = *(const float4*)(gx + 4);
            uint4 o;
            o.x = pack2(a.x, a.y); o.y = pack2(a.z, a.w);
            o.z = pack2(b.x, b.y); o.w = pack2(b.z, b.w);
            int byte = (row * BK + kk) * 2;
            byte ^= (row & 7) << 4;
            *(uint4*)((char*)xs + byte) = o;
        }
#pragma unroll
        for (int p = 0; p < 4; ++p) {
            int l  = p * 32 + (tid >> 3);
            int kk = (tid & 7) * 8;
            uint4 v = *(const uint4*)(Vh + (size_t)l * M_ + k0 + kk);
            uint4 u = *(const uint4*)(Uh + (size_t)l * M_ + k0 + kk);
            int byte = (l * BK + kk) * 2;
            byte ^= (l & 7) << 4;
            *(uint4*)((char*)vs + byte) = v;
            *(uint4*)((char*)us + byte) = u;
        }
        __syncthreads();
#pragma unroll
        for (int ksub = 0; ksub < 2; ++ksub) {
            bf16x8 afr[2];
#pragma unroll
            for (int rf = 0; rf < 2; ++rf) {
                int row = wave * 32 + rf * 16 + c;
                int byte = (row * BK + ksub * 32 + g * 8) * 2;
                byte ^= (row & 7) << 4;
                afr[rf] = *(const bf16x8*)((const char*)xs + byte);
            }
#pragma unroll
            for (int cf = 0; cf < 8; ++cf) {
                int l = cf * 16 + c;
                int byte = (l * BK + ksub * 32 + g * 8) * 2;
                byte ^= (l & 7) << 4;
                bf16x8 bv = *(const bf16x8*)((const char*)vs + byte);
                bf16x8 bu = *(const bf16x8*)((const char*)us + byte);
#pragma unroll
                for (int rf = 0; rf < 2; ++rf) {
                    accV[rf][cf] = __builtin_amdgcn_mfma_f32_16x16x32_bf16(afr[rf], bv, accV[rf][cf], 0, 0, 0);
                    accU[rf][cf] = __builtin_amdgcn_mfma_f32_16x16x32_bf16(afr[rf], bu, accU[rf][cf], 0, 0, 0);
                }
            }
        }
    }
#pragma unroll
    for (int rf = 0; rf < 2; ++rf) {
        float plog[4] = {0.f, 0.f, 0.f, 0.f};
#pragma unroll
        for (int cf = 0; cf < 8; ++cf) {
            float wvv = wl[cf * 16 + c];
#pragma unroll
            for (int i = 0; i < 4; ++i) {
                float vv = accV[rf][cf][i];
                float uu = accU[rf][cf][i];
                vv = fminf(fmaxf(vv, -20.f), 20.f);
                float e2v = __expf(2.f * vv);
                float t = __fdividef(e2v - 1.f, e2v + 1.f);
                float s = __fdividef(1.f, 1.f + __expf(-uu));
                plog[i] += t * s * wvv;
            }
        }
#pragma unroll
        for (int i = 0; i < 4; ++i) {
            float v = plog[i];
            v += __shfl_xor(v, 1);
            v += __shfl_xor(v, 2);
            v += __shfl_xor(v, 4);
            v += __shfl_xor(v, 8);
            if (c == 0) {
                int rowflat = row0 + wave * 32 + rf * 16 + g * 4 + i;
                int b = rowflat >> 12;
                int n = rowflat & (N_ - 1);
                logits[((size_t)b * H_ + h) * N_ + n] = v;
            }
        }
    }
}

// ---------------------------------------------------------------------------
// softmax^2 (first normalization cancels): a = e^2/sum(e^2), e = m*exp(m*l).
// ---------------------------------------------------------------------------
__global__ __launch_bounds__(256)
void softmax_att(const float* __restrict__ logits, const float* __restrict__ masks,
                 float* __restrict__ att) {
    const int bh = blockIdx.x;
    const int b = bh >> 2, h = bh & 3;
    __shared__ float e2s[N_];
    __shared__ float red[4];
    const int tid = threadIdx.x;

    float sum = 0.f;
#pragma unroll
    for (int i = 0; i < N_ / 256; ++i) {
        int n = i * 256 + tid;
        float lg = logits[((size_t)b * H_ + h) * N_ + n];
        float mv = masks[(size_t)b * N_ + n];
        float e = mv * __expf(mv * lg);
        float e2 = e * e;
        e2s[n] = e2;
        sum += e2;
    }
#pragma unroll
    for (int off = 32; off >= 1; off >>= 1) sum += __shfl_xor(sum, off);
    if ((tid & 63) == 0) red[tid >> 6] = sum;
    __syncthreads();
    float S = red[0] + red[1] + red[2] + red[3];
    float inv = 1.f / S;
#pragma unroll
    for (int i = 0; i < N_ / 256; ++i) {
        int n = i * 256 + tid;
        att[((size_t)h * B_ + b) * N_ + n] = e2s[n] * inv;
    }
}

// ---------------------------------------------------------------------------
// emb: 2-stage deterministic reduction.
// ---------------------------------------------------------------------------
#define NCH 32
#define CHUNK (N_ / NCH)   // 128

__global__ __launch_bounds__(256)
void emb_partial(const float* __restrict__ x, const float* __restrict__ att,
                 float* __restrict__ part) {
    const int bc = blockIdx.x;
    const int b = bc >> 5, ch = bc & 31;
    __shared__ float as[H_][CHUNK];
    const int tid = threadIdx.x;

    for (int i = tid; i < H_ * CHUNK; i += 256) {
        int hh = i >> 7;
        int j  = i & (CHUNK - 1);
        as[hh][j] = att[((size_t)hh * B_ + b) * N_ + ch * CHUNK + j];
    }
    __syncthreads();

    float a0 = 0.f, a1 = 0.f, a2 = 0.f, a3 = 0.f;
    const float* xp = x + ((size_t)b * N_ + ch * CHUNK) * M_ + tid;
#pragma unroll 4
    for (int j = 0; j < CHUNK; ++j) {
        float xv = xp[(size_t)j * M_];
        a0 += as[0][j] * xv;
        a1 += as[1][j] * xv;
        a2 += as[2][j] * xv;
        a3 += as[3][j] * xv;
    }
    float* pp = part + (size_t)bc * H_ * M_ + tid;
    pp[0 * M_] = a0; pp[1 * M_] = a1; pp[2 * M_] = a2; pp[3 * M_] = a3;
}

__global__ __launch_bounds__(256)
void emb_reduce(const float* __restrict__ part, float* __restrict__ emb) {
    int idx = blockIdx.x * 256 + threadIdx.x;
    int b = idx >> 10;
    int r = idx & 1023;
    float s = 0.f;
#pragma unroll
    for (int ci = 0; ci < NCH; ++ci)
        s += part[((size_t)(b * NCH + ci)) * (H_ * M_) + r];
    emb[idx] = s;
}

// ---------------------------------------------------------------------------
extern "C" void kernel_launch(void* const* d_in, const int* in_sizes, int n_in,
                              void* d_out, int out_size, void* d_ws, size_t ws_size,
                              hipStream_t stream) {
    const float* x     = (const float*)d_in[0];
    const float* masks = (const float*)d_in[1];
    const float* V     = (const float*)d_in[2];
    const float* U     = (const float*)d_in[3];
    const float* w     = (const float*)d_in[4];

    float* att = (float*)d_out;                       // (H,B,N,1)
    float* emb = att + (size_t)H_ * B_ * N_;          // (B,H*M)

    char* ws = (char*)d_ws;
    const size_t VU_BYTES  = (size_t)64 * 8192;               // 524,288
    const size_t LG_BYTES  = (size_t)B_ * H_ * N_ * 4;        // 2,097,152
    const size_t PT_BYTES  = (size_t)B_ * NCH * H_ * M_ * 4;  // 4,194,304
    const size_t NEED_FAST = VU_BYTES + LG_BYTES + PT_BYTES;

    float* logits;
    float* partp;

    if (ws_size >= NEED_FAST) {
        unsigned short* vuimg = (unsigned short*)ws;
        logits = (float*)(ws + VU_BYTES);
        partp  = (float*)(ws + VU_BYTES + LG_BYTES);

        prep_vu_img<<<32,   256, 0, stream>>>(V, U, vuimg);
        gemm_fast7 <<<4096, 256, 0, stream>>>(x, vuimg, w, logits);
    } else {
        unsigned short* Vt = (unsigned short*)ws;
        unsigned short* Ut = (unsigned short*)(ws + 262144);
        logits = (float*)(ws + 524288);
        partp  = (float*)(ws + 524288 + LG_BYTES);

        prep_vu_slow<<<512, 256, 0, stream>>>(V, U, Vt, Ut);
        gemm_logits <<<4096, 256, 0, stream>>>(x, Vt, Ut, w, logits);
    }

    softmax_att<<<B_ * H_,              256, 0, stream>>>(logits, masks, att);
    emb_partial<<<B_ * NCH,             256, 0, stream>>>(x, att, partp);
    emb_reduce <<<(B_ * H_ * M_) / 256, 256, 0, stream>>>(partp, emb);
}

// Round 10
// 168.668 us; speedup vs baseline: 1.3035x; 1.3035x over previous
//
#include <hip/hip_runtime.h>
#include <hip/hip_bf16.h>
#include <stdint.h>

// Problem constants
#define B_ 32
#define N_ 4096
#define M_ 256
#define L_ 128
#define H_ 4
#define BN_ (B_ * N_)          // 131072 flattened rows

typedef __bf16 bf16x8 __attribute__((ext_vector_type(8)));
typedef float  f32x4  __attribute__((ext_vector_type(4)));

__device__ __forceinline__ unsigned short f2bf(float f) {
    // round-to-nearest-even f32 -> bf16
    unsigned int u = __float_as_uint(f);
    u += 0x7fffu + ((u >> 16) & 1u);
    return (unsigned short)(u >> 16);
}
__device__ __forceinline__ unsigned int pack2(float lo, float hi) {
    return (unsigned int)f2bf(lo) | ((unsigned int)f2bf(hi) << 16);
}

// async global->LDS, 16B per lane. LDS dest is wave-uniform base (+lane*16 by HW);
// global src is per-lane (m173: pre-permute the SOURCE to realize a swizzled
// LDS layout while keeping the LDS destination linear).
__device__ __forceinline__ void gload16(const void* g, void* l) {
    __builtin_amdgcn_global_load_lds(
        (const __attribute__((address_space(1))) unsigned int*)g,
        (__attribute__((address_space(3))) unsigned int*)l, 16, 0, 0);
}

// ---------------------------------------------------------------------------
// prep: V,U (H,M,L) f32 -> vu images [(h*8 + s)*2 + mat][128 l][32 m] bf16,
// swizzled (byte ^= (l&14)<<3), PRESCALED: V *= 2, U *= -1 so the GEMM
// epilogue is A=exp(accV)=e^{2v}, E=exp(accU)=e^{-u}.
// ---------------------------------------------------------------------------
__global__ void prep_vu_img(const float* __restrict__ V, const float* __restrict__ U,
                            unsigned short* __restrict__ vu) {
    __shared__ float slab[64][129];     // [m][l], padded
    const int b   = blockIdx.x;         // 32 = h(4) * ks64(4) * mat(2)
    const int mat = b & 1, ks = (b >> 1) & 3, h = b >> 3;
    const float* src = (mat ? U : V) + ((size_t)h * M_ + ks * 64) * L_;
    const float scale = mat ? -1.0f : 2.0f;
    const int tid = threadIdx.x;
#pragma unroll
    for (int rep = 0; rep < 32; ++rep) {
        int idx = rep * 256 + tid;      // 8192 = 64m x 128l
        slab[idx >> 7][idx & 127] = scale * src[(size_t)(idx >> 7) * L_ + (idx & 127)];
    }
    __syncthreads();
#pragma unroll
    for (int rep = 0; rep < 4; ++rep) {
        int cidx = rep * 256 + tid;     // 1024 chunks of 16B (two 8KB images)
        int l  = cidx >> 3;             // 0..127
        int kk = (cidx & 7) * 8;        // 0..56
        uint4 o;
        o.x = pack2(slab[kk + 0][l], slab[kk + 1][l]);
        o.y = pack2(slab[kk + 2][l], slab[kk + 3][l]);
        o.z = pack2(slab[kk + 4][l], slab[kk + 5][l]);
        o.w = pack2(slab[kk + 6][l], slab[kk + 7][l]);
        int tl = kk >> 5, kl = kk & 31;
        char* dst = (char*)vu + (((size_t)(h * 8 + ks * 2 + tl)) * 2 + mat) * 8192;
        int byte = (l * 64 + kl * 2) ^ ((l & 14) << 3);
        *(uint4*)(dst + byte) = o;
    }
}

// ---------------------------------------------------------------------------
// gemm_fast8: x staged DIRECTLY from its f32 HBM layout via gload16 with
// pre-swizzled per-lane sources (no prep_x, no xb round-trip, no reg staging).
// x lives in LDS as f32 [128 rows][32 k], row stride 128B, swizzled
// byte ^= (row&7)<<4; A-fragments are converted f32->bf16 at read time
// (2x ds_read_b128 + 8 scalar casts -> v_cvt_pk, consumed immediately).
// V/U stay on the proven bf16-image gload16 path (round 8).
// 64x64 wave tiles; per step/wave: 8 A-reads(f32) + 8 B-reads + 32 MFMA.
// 2-buffer LDS (65KB -> 2 blocks/CU), 1-deep prefetch, vmcnt(0)+barrier,
// T5 setprio. Grid: h-inner + bijective XCD swizzle.
// ---------------------------------------------------------------------------
__global__ __launch_bounds__(256, 2)
void gemm_fast8(const float* __restrict__ x,
                const unsigned short* __restrict__ vu,
                const float* __restrict__ w,
                float* __restrict__ logits) {
    __shared__ __align__(16) float          xs[2][4096];   // 2 x 16KB (f32!)
    __shared__ __align__(16) unsigned short vs[2][4096];   // 2 x 8KB
    __shared__ __align__(16) unsigned short us[2][4096];   // 2 x 8KB
    __shared__ float part[2][128];

    const int orig    = blockIdx.x;                 // 4096, %8==0 -> bijective
    const int logical = (orig & 7) * 512 + (orig >> 3);
    const int tile    = logical >> 2;
    const int h       = logical & 3;

    const int tid  = threadIdx.x;
    const int lane = tid & 63;
    const int wv   = tid >> 6;
    const int g    = lane >> 4;     // k-group 0..3
    const int c    = lane & 15;     // row (A) / col (B) within fragment
    const int wr   = wv & 1;        // wave row half
    const int wc   = wv >> 1;       // wave l half

    f32x4 accV[4][4], accU[4][4];
#pragma unroll
    for (int rf = 0; rf < 4; ++rf)
#pragma unroll
        for (int cf = 0; cf < 4; ++cf) {
            accV[rf][cf] = (f32x4){0.f, 0.f, 0.f, 0.f};
            accU[rf][cf] = (f32x4){0.f, 0.f, 0.f, 0.f};
        }

    const int soff = wv * 2048;     // wave's quarter of each 8KB B-image

    // B global sources (pre-swizzled prescaled images; step stride 16384 B)
    const char* gvs = (const char*)vu + (size_t)h * 131072 + soff + lane * 16;
    const char* gus = gvs + 8192;

    // x staging source (derived from LDS-linear dest + inverse swizzle):
    //   dest s = wv*4096 + j*1024 + lane*16  ->  row = wv*32 + j*8 + (lane>>3)
    //   cb = ((lane&7)*16) ^ ((lane>>3)<<4)   (j-independent)
    //   global byte = row*1024 + t*128 + cb ;  j adds 8192, step adds 128.
    const int cb = ((lane & 7) * 16) ^ ((lane >> 3) << 4);
    const char* gxl = (const char*)x
        + ((size_t)tile * 128 + wv * 32 + (lane >> 3)) * 1024 + cb;

    // A-frag read offsets (f32 image, row stride 128B, swizzle (r&7)<<4):
    int aoff[4], boff[4];
#pragma unroll
    for (int rf = 0; rf < 4; ++rf) {
        int r = wr * 64 + rf * 16 + c;
        aoff[rf] = (r * 128 + g * 32) ^ ((r & 7) << 4);
    }
#pragma unroll
    for (int cf = 0; cf < 4; ++cf) {
        int l = wc * 64 + cf * 16 + c;
        boff[cf] = (l * 64 + g * 16) ^ ((l & 14) << 3);
    }

#define SCHED __builtin_amdgcn_sched_barrier(0)

#define STAGEX(t, bufi) do {                                         \
        const char* _g = gxl + (t) * 128;                            \
        char* _d = (char*)xs[bufi] + wv * 4096;                      \
        gload16(_g,          _d);                                    \
        gload16(_g + 8192,   _d + 1024);                             \
        gload16(_g + 16384,  _d + 2048);                             \
        gload16(_g + 24576,  _d + 3072);                             \
    } while (0)

#define STAGEB(t, bufi) do {                                         \
        const char* _gv = gvs + (t) * 16384;                         \
        const char* _gu = gus + (t) * 16384;                         \
        gload16(_gv,        (char*)vs[bufi] + soff);                 \
        gload16(_gv + 1024, (char*)vs[bufi] + soff + 1024);          \
        gload16(_gu,        (char*)us[bufi] + soff);                 \
        gload16(_gu + 1024, (char*)us[bufi] + soff + 1024);          \
    } while (0)

    // prologue: stage step 0 into buf 0 (8 loads per wave)
    STAGEX(0, 0);
    STAGEB(0, 0);
    SCHED;

#pragma unroll
    for (int t = 0; t < 8; ++t) {
        // stage(t) was issued a full step ago -> latency covered.
        asm volatile("s_waitcnt vmcnt(0)" ::: "memory");
        __builtin_amdgcn_s_barrier();
        SCHED;

        if (t < 7) {
            STAGEX(t + 1, (t + 1) & 1);
            STAGEB(t + 1, (t + 1) & 1);
        }
        SCHED;

        const int buf = t & 1;          // compile-time after unroll
        const float* xbuf = xs[buf];
        const char*  vbuf = (const char*)vs[buf];
        const char*  ubuf = (const char*)us[buf];

        bf16x8 bv[4], bu[4];
#pragma unroll
        for (int cf = 0; cf < 4; ++cf) {
            bv[cf] = *(const bf16x8*)(vbuf + boff[cf]);
            bu[cf] = *(const bf16x8*)(ubuf + boff[cf]);
        }
        __builtin_amdgcn_s_setprio(1);
#pragma unroll
        for (int rf = 0; rf < 4; ++rf) {
            f32x4 p = *(const f32x4*)((const char*)xbuf + aoff[rf]);
            f32x4 q = *(const f32x4*)((const char*)xbuf + (aoff[rf] ^ 16));
            bf16x8 a;
            a[0] = (__bf16)p.x; a[1] = (__bf16)p.y;
            a[2] = (__bf16)p.z; a[3] = (__bf16)p.w;
            a[4] = (__bf16)q.x; a[5] = (__bf16)q.y;
            a[6] = (__bf16)q.z; a[7] = (__bf16)q.w;
#pragma unroll
            for (int cf = 0; cf < 4; ++cf) {
                accV[rf][cf] = __builtin_amdgcn_mfma_f32_16x16x32_bf16(a, bv[cf], accV[rf][cf], 0, 0, 0);
                accU[rf][cf] = __builtin_amdgcn_mfma_f32_16x16x32_bf16(a, bu[cf], accU[rf][cf], 0, 0, 0);
            }
        }
        __builtin_amdgcn_s_setprio(0);
    }
#undef STAGEB
#undef STAGEX
#undef SCHED

    // ---- epilogue: V prescaled by 2, U by -1 -> A=e^{2v}, E=e^{-u}.
    //      gated = (A-1)/((A+1)(1+E)); dot w over wave's 64 l; 16-lane
    //      shuffle reduce; join l-halves via LDS part[]. (|acc| << 88.)
    const float* wrow = w + h * L_ + wc * 64;
#pragma unroll
    for (int rf = 0; rf < 4; ++rf) {
        float plog[4] = {0.f, 0.f, 0.f, 0.f};
#pragma unroll
        for (int cf = 0; cf < 4; ++cf) {
            float wvv = wrow[cf * 16 + c];
#pragma unroll
            for (int i = 0; i < 4; ++i) {
                float A = __expf(accV[rf][cf][i]);
                float E = __expf(accU[rf][cf][i]);
                float gg = __fdividef(A - 1.f, (A + 1.f) * (1.f + E));
                plog[i] += gg * wvv;
            }
        }
#pragma unroll
        for (int i = 0; i < 4; ++i) {
            float v = plog[i];
            v += __shfl_xor(v, 1);
            v += __shfl_xor(v, 2);
            v += __shfl_xor(v, 4);
            v += __shfl_xor(v, 8);      // sum over the 16 col-lanes
            if (c == 0)
                part[wc][wr * 64 + rf * 16 + g * 4 + i] = v;
        }
    }
    __syncthreads();
    if (tid < 128) {
        float v = part[0][tid] + part[1][tid];
        int rowflat = tile * 128 + tid;
        int b = rowflat >> 12;           // / N_
        int n = rowflat & (N_ - 1);
        logits[((size_t)b * H_ + h) * N_ + n] = v;
    }
}

// ---------------------------------------------------------------------------
// SLOW PATH (round-1 fallback, used only if ws_size is too small)
// ---------------------------------------------------------------------------
__global__ void prep_vu_slow(const float* __restrict__ V, const float* __restrict__ U,
                             unsigned short* __restrict__ Vt, unsigned short* __restrict__ Ut) {
    int idx = blockIdx.x * 256 + threadIdx.x;
    int m = idx & (M_ - 1);
    int l = (idx >> 8) & (L_ - 1);
    int h = idx >> 15;
    Vt[idx] = f2bf(V[((size_t)h * M_ + m) * L_ + l]);
    Ut[idx] = f2bf(U[((size_t)h * M_ + m) * L_ + l]);
}

#define BM 128
#define BK 64

__global__ __launch_bounds__(256, 2)
void gemm_logits(const float* __restrict__ x,
                 const unsigned short* __restrict__ Vt,
                 const unsigned short* __restrict__ Ut,
                 const float* __restrict__ w,
                 float* __restrict__ logits) {
    __shared__ __align__(16) unsigned short xs[BM * BK];
    __shared__ __align__(16) unsigned short vs[L_ * BK];
    __shared__ __align__(16) unsigned short us[L_ * BK];
    __shared__ float wl[L_];

    const int h    = blockIdx.x >> 10;
    const int tile = blockIdx.x & 1023;
    const int row0 = tile * BM;
    const int tid  = threadIdx.x;
    const int lane = tid & 63;
    const int wave = tid >> 6;

    if (tid < L_) wl[tid] = w[h * L_ + tid];

    f32x4 accV[2][8], accU[2][8];
#pragma unroll
    for (int rf = 0; rf < 2; ++rf)
#pragma unroll
        for (int cf = 0; cf < 8; ++cf) {
            accV[rf][cf] = (f32x4){0.f, 0.f, 0.f, 0.f};
            accU[rf][cf] = (f32x4){0.f, 0.f, 0.f, 0.f};
        }

    const unsigned short* Vh = Vt + (size_t)h * L_ * M_;
    const unsigned short* Uh = Ut + (size_t)h * L_ * M_;
    const int g = lane >> 4;
    const int c = lane & 15;

    for (int ks = 0; ks < 4; ++ks) {
        const int k0 = ks * BK;
        __syncthreads();
#pragma unroll
        for (int p = 0; p < 4; ++p) {
            int row = p * 32 + (tid >> 3);
            int kk  = (tid & 7) * 8;
            const float* gx = x + (size_t)(row0 + row) * M_ + k0 + kk;
            float4 a = *(const float4*)gx;
            float4 b = *(const float4*)(gx + 4);
            uint4 o;
            o.x = pack2(a.x, a.y); o.y = pack2(a.z, a.w);
            o.z = pack2(b.x, b.y); o.w = pack2(b.z, b.w);
            int byte = (row * BK + kk) * 2;
            byte ^= (row & 7) << 4;
            *(uint4*)((char*)xs + byte) = o;
        }
#pragma unroll
        for (int p = 0; p < 4; ++p) {
            int l  = p * 32 + (tid >> 3);
            int kk = (tid & 7) * 8;
            uint4 v = *(const uint4*)(Vh + (size_t)l * M_ + k0 + kk);
            uint4 u = *(const uint4*)(Uh + (size_t)l * M_ + k0 + kk);
            int byte = (l * BK + kk) * 2;
            byte ^= (l & 7) << 4;
            *(uint4*)((char*)vs + byte) = v;
            *(uint4*)((char*)us + byte) = u;
        }
        __syncthreads();
#pragma unroll
        for (int ksub = 0; ksub < 2; ++ksub) {
            bf16x8 afr[2];
#pragma unroll
            for (int rf = 0; rf < 2; ++rf) {
                int row = wave * 32 + rf * 16 + c;
                int byte = (row * BK + ksub * 32 + g * 8) * 2;
                byte ^= (row & 7) << 4;
                afr[rf] = *(const bf16x8*)((const char*)xs + byte);
            }
#pragma unroll
            for (int cf = 0; cf < 8; ++cf) {
                int l = cf * 16 + c;
                int byte = (l * BK + ksub * 32 + g * 8) * 2;
                byte ^= (l & 7) << 4;
                bf16x8 bv = *(const bf16x8*)((const char*)vs + byte);
                bf16x8 bu = *(const bf16x8*)((const char*)us + byte);
#pragma unroll
                for (int rf = 0; rf < 2; ++rf) {
                    accV[rf][cf] = __builtin_amdgcn_mfma_f32_16x16x32_bf16(afr[rf], bv, accV[rf][cf], 0, 0, 0);
                    accU[rf][cf] = __builtin_amdgcn_mfma_f32_16x16x32_bf16(afr[rf], bu, accU[rf][cf], 0, 0, 0);
                }
            }
        }
    }
#pragma unroll
    for (int rf = 0; rf < 2; ++rf) {
        float plog[4] = {0.f, 0.f, 0.f, 0.f};
#pragma unroll
        for (int cf = 0; cf < 8; ++cf) {
            float wvv = wl[cf * 16 + c];
#pragma unroll
            for (int i = 0; i < 4; ++i) {
                float vv = accV[rf][cf][i];
                float uu = accU[rf][cf][i];
                vv = fminf(fmaxf(vv, -20.f), 20.f);
                float e2v = __expf(2.f * vv);
                float t = __fdividef(e2v - 1.f, e2v + 1.f);
                float s = __fdividef(1.f, 1.f + __expf(-uu));
                plog[i] += t * s * wvv;
            }
        }
#pragma unroll
        for (int i = 0; i < 4; ++i) {
            float v = plog[i];
            v += __shfl_xor(v, 1);
            v += __shfl_xor(v, 2);
            v += __shfl_xor(v, 4);
            v += __shfl_xor(v, 8);
            if (c == 0) {
                int rowflat = row0 + wave * 32 + rf * 16 + g * 4 + i;
                int b = rowflat >> 12;
                int n = rowflat & (N_ - 1);
                logits[((size_t)b * H_ + h) * N_ + n] = v;
            }
        }
    }
}

// ---------------------------------------------------------------------------
// softmax^2 (first normalization cancels): a = e^2/sum(e^2), e = m*exp(m*l).
// ---------------------------------------------------------------------------
__global__ __launch_bounds__(256)
void softmax_att(const float* __restrict__ logits, const float* __restrict__ masks,
                 float* __restrict__ att) {
    const int bh = blockIdx.x;
    const int b = bh >> 2, h = bh & 3;
    __shared__ float e2s[N_];
    __shared__ float red[4];
    const int tid = threadIdx.x;

    float sum = 0.f;
#pragma unroll
    for (int i = 0; i < N_ / 256; ++i) {
        int n = i * 256 + tid;
        float lg = logits[((size_t)b * H_ + h) * N_ + n];
        float mv = masks[(size_t)b * N_ + n];
        float e = mv * __expf(mv * lg);
        float e2 = e * e;
        e2s[n] = e2;
        sum += e2;
    }
#pragma unroll
    for (int off = 32; off >= 1; off >>= 1) sum += __shfl_xor(sum, off);
    if ((tid & 63) == 0) red[tid >> 6] = sum;
    __syncthreads();
    float S = red[0] + red[1] + red[2] + red[3];
    float inv = 1.f / S;
#pragma unroll
    for (int i = 0; i < N_ / 256; ++i) {
        int n = i * 256 + tid;
        att[((size_t)h * B_ + b) * N_ + n] = e2s[n] * inv;
    }
}

// ---------------------------------------------------------------------------
// emb: 2-stage deterministic reduction.
// ---------------------------------------------------------------------------
#define NCH 32
#define CHUNK (N_ / NCH)   // 128

__global__ __launch_bounds__(256)
void emb_partial(const float* __restrict__ x, const float* __restrict__ att,
                 float* __restrict__ part) {
    const int bc = blockIdx.x;
    const int b = bc >> 5, ch = bc & 31;
    __shared__ float as[H_][CHUNK];
    const int tid = threadIdx.x;

    for (int i = tid; i < H_ * CHUNK; i += 256) {
        int hh = i >> 7;
        int j  = i & (CHUNK - 1);
        as[hh][j] = att[((size_t)hh * B_ + b) * N_ + ch * CHUNK + j];
    }
    __syncthreads();

    float a0 = 0.f, a1 = 0.f, a2 = 0.f, a3 = 0.f;
    const float* xp = x + ((size_t)b * N_ + ch * CHUNK) * M_ + tid;
#pragma unroll 4
    for (int j = 0; j < CHUNK; ++j) {
        float xv = xp[(size_t)j * M_];
        a0 += as[0][j] * xv;
        a1 += as[1][j] * xv;
        a2 += as[2][j] * xv;
        a3 += as[3][j] * xv;
    }
    float* pp = part + (size_t)bc * H_ * M_ + tid;
    pp[0 * M_] = a0; pp[1 * M_] = a1; pp[2 * M_] = a2; pp[3 * M_] = a3;
}

__global__ __launch_bounds__(256)
void emb_reduce(const float* __restrict__ part, float* __restrict__ emb) {
    int idx = blockIdx.x * 256 + threadIdx.x;
    int b = idx >> 10;
    int r = idx & 1023;
    float s = 0.f;
#pragma unroll
    for (int ci = 0; ci < NCH; ++ci)
        s += part[((size_t)(b * NCH + ci)) * (H_ * M_) + r];
    emb[idx] = s;
}

// ---------------------------------------------------------------------------
extern "C" void kernel_launch(void* const* d_in, const int* in_sizes, int n_in,
                              void* d_out, int out_size, void* d_ws, size_t ws_size,
                              hipStream_t stream) {
    const float* x     = (const float*)d_in[0];
    const float* masks = (const float*)d_in[1];
    const float* V     = (const float*)d_in[2];
    const float* U     = (const float*)d_in[3];
    const float* w     = (const float*)d_in[4];

    float* att = (float*)d_out;                       // (H,B,N,1)
    float* emb = att + (size_t)H_ * B_ * N_;          // (B,H*M)

    char* ws = (char*)d_ws;
    const size_t VU_BYTES  = (size_t)64 * 8192;               // 524,288
    const size_t LG_BYTES  = (size_t)B_ * H_ * N_ * 4;        // 2,097,152
    const size_t PT_BYTES  = (size_t)B_ * NCH * H_ * M_ * 4;  // 4,194,304
    const size_t NEED_FAST = VU_BYTES + LG_BYTES + PT_BYTES;

    float* logits;
    float* partp;

    if (ws_size >= NEED_FAST) {
        unsigned short* vuimg = (unsigned short*)ws;
        logits = (float*)(ws + VU_BYTES);
        partp  = (float*)(ws + VU_BYTES + LG_BYTES);

        prep_vu_img<<<32,   256, 0, stream>>>(V, U, vuimg);
        gemm_fast8 <<<4096, 256, 0, stream>>>(x, vuimg, w, logits);
    } else {
        unsigned short* Vt = (unsigned short*)ws;
        unsigned short* Ut = (unsigned short*)(ws + 262144);
        logits = (float*)(ws + 524288);
        partp  = (float*)(ws + 524288 + LG_BYTES);

        prep_vu_slow<<<512, 256, 0, stream>>>(V, U, Vt, Ut);
        gemm_logits <<<4096, 256, 0, stream>>>(x, Vt, Ut, w, logits);
    }

    softmax_att<<<B_ * H_,              256, 0, stream>>>(logits, masks, att);
    emb_partial<<<B_ * NCH,             256, 0, stream>>>(x, att, partp);
    emb_reduce <<<(B_ * H_ * M_) / 256, 256, 0, stream>>>(partp, emb);
}

// Round 11
// 159.903 us; speedup vs baseline: 1.3749x; 1.0548x over previous
//
#include <hip/hip_runtime.h>
#include <hip/hip_bf16.h>
#include <stdint.h>

// Problem constants
#define B_ 32
#define N_ 4096
#define M_ 256
#define L_ 128
#define H_ 4
#define BN_ (B_ * N_)          // 131072 flattened rows

typedef __bf16 bf16x8 __attribute__((ext_vector_type(8)));
typedef float  f32x4  __attribute__((ext_vector_type(4)));

__device__ __forceinline__ unsigned short f2bf(float f) {
    unsigned int u = __float_as_uint(f);
    u += 0x7fffu + ((u >> 16) & 1u);
    return (unsigned short)(u >> 16);
}
__device__ __forceinline__ unsigned int pack2(float lo, float hi) {
    return (unsigned int)f2bf(lo) | ((unsigned int)f2bf(hi) << 16);
}

// async global->LDS, 16B/lane; LDS dest wave-uniform base + lane*16 (HW);
// global src per-lane (m173: pre-permute SOURCE to realize a swizzled layout).
__device__ __forceinline__ void gload16(const void* g, void* l) {
    __builtin_amdgcn_global_load_lds(
        (const __attribute__((address_space(1))) unsigned int*)g,
        (__attribute__((address_space(3))) unsigned int*)l, 16, 0, 0);
}

// ---------------------------------------------------------------------------
// prep: V,U (H,M,L) f32 -> vu2 4KB images [(((h*2+lh)*8 + s)*2 + mat)]
// [64 l][32 m] bf16, swizzle byte ^= (ll&14)<<3, PRESCALED (V*=2, U*=-1).
// ---------------------------------------------------------------------------
__global__ void prep_vu_img2(const float* __restrict__ V, const float* __restrict__ U,
                             unsigned short* __restrict__ vu) {
    __shared__ float slab[64][129];     // [m][l], padded
    const int b   = blockIdx.x;         // 32 = h(4) * ks64(4) * mat(2)
    const int mat = b & 1, ks = (b >> 1) & 3, h = b >> 3;
    const float* src = (mat ? U : V) + ((size_t)h * M_ + ks * 64) * L_;
    const float scale = mat ? -1.0f : 2.0f;
    const int tid = threadIdx.x;
#pragma unroll
    for (int rep = 0; rep < 32; ++rep) {
        int idx = rep * 256 + tid;      // 8192 = 64m x 128l
        slab[idx >> 7][idx & 127] = scale * src[(size_t)(idx >> 7) * L_ + (idx & 127)];
    }
    __syncthreads();
#pragma unroll
    for (int rep = 0; rep < 4; ++rep) {
        int cidx = rep * 256 + tid;     // 1024 chunks of 16B
        int l  = cidx >> 3;             // 0..127
        int kk = (cidx & 7) * 8;        // 0..56
        uint4 o;
        o.x = pack2(slab[kk + 0][l], slab[kk + 1][l]);
        o.y = pack2(slab[kk + 2][l], slab[kk + 3][l]);
        o.z = pack2(slab[kk + 4][l], slab[kk + 5][l]);
        o.w = pack2(slab[kk + 6][l], slab[kk + 7][l]);
        int tl = kk >> 5, kl = kk & 31;
        int lh = l >> 6, ll = l & 63;
        char* dst = (char*)vu
            + ((((size_t)(h * 2 + lh) * 8 + (ks * 2 + tl)) * 2) + mat) * 4096;
        int byte = (ll * 64 + kl * 2) ^ ((ll & 14) << 3);
        *(uint4*)(dst + byte) = o;
    }
}

// ---------------------------------------------------------------------------
// gemm_fast10: high-occupancy (3 waves/SIMD) fused GEMM.
// Block = 128 rows x 64 l x {V,U} for one (tile, h, lh); 4 waves, wave wv owns
// rows wv*32..+32, all 64 l. acc = 2rf x 4cf x {V,U} = 64 VGPR -> total regs
// ~140 -> 3 waves/SIMD; LDS 48KB -> 3 blocks/CU. Writes PARTIAL logits (per
// l-half); softmax sums the two halves (deterministic).
// x staged inline as f32 via gload16 (pre-swizzled per-lane source, swizzle
// byte ^= (row&14)<<3 on 128B rows), converted f32->bf16 at fragment read.
// B from 4KB prescaled bf16 images. 1-deep prefetch, vmcnt(0)+barrier/step.
// ---------------------------------------------------------------------------
__global__ __launch_bounds__(256, 3)
void gemm_fast10(const float* __restrict__ x,
                 const unsigned short* __restrict__ vu,
                 const float* __restrict__ w,
                 float* __restrict__ partL) {
    __shared__ __align__(16) float          xs[2][4096];   // 2 x 16KB f32
    __shared__ __align__(16) unsigned short vs[2][2048];   // 2 x 4KB
    __shared__ __align__(16) unsigned short us[2][2048];   // 2 x 4KB

    const int orig    = blockIdx.x;                 // 8192, %8==0 -> bijective
    const int logical = (orig & 7) * 1024 + (orig >> 3);
    const int tile    = logical >> 3;
    const int h       = (logical >> 1) & 3;
    const int lh      = logical & 1;

    const int tid  = threadIdx.x;
    const int lane = tid & 63;
    const int wv   = tid >> 6;
    const int g    = lane >> 4;     // k-group 0..3
    const int c    = lane & 15;     // row (A) / col (B) within fragment

    f32x4 accV[2][4], accU[2][4];   // 64 VGPR total
#pragma unroll
    for (int rf = 0; rf < 2; ++rf)
#pragma unroll
        for (int cf = 0; cf < 4; ++cf) {
            accV[rf][cf] = (f32x4){0.f, 0.f, 0.f, 0.f};
            accU[rf][cf] = (f32x4){0.f, 0.f, 0.f, 0.f};
        }

    // ---- B global sources: 4KB images, step stride 8192B (v+u) ----
    const char* gvs = (const char*)vu + (size_t)(h * 2 + lh) * 65536
                      + wv * 1024 + lane * 16;
    const char* gus = gvs + 4096;

    // ---- x staging source (inverse-swizzled per-lane addresses) ----
    // dest s = wv*4096 + j*1024 + lane*16 -> row = wv*32 + j*8 + (lane>>3),
    // off = (lane&7)*16 ^ ((row&14)<<3); key bits4-5 from lane>>3, bit6 from j&1.
    const int offb = ((lane & 7) << 4) ^ (((lane >> 3) & 6) << 3);
    const char* pA = (const char*)x
        + ((size_t)tile * 128 + wv * 32 + (lane >> 3)) * 1024 + offb;        // j even
    const char* pB = (const char*)x
        + ((size_t)tile * 128 + wv * 32 + (lane >> 3)) * 1024 + (offb ^ 64); // j odd

    // ---- LDS read offsets ----
    int aoff[2], boff[4];
#pragma unroll
    for (int rf = 0; rf < 2; ++rf) {
        int r = wv * 32 + rf * 16 + c;
        aoff[rf] = (r * 128 + g * 32) ^ ((c & 14) << 3);
    }
#pragma unroll
    for (int cf = 0; cf < 4; ++cf) {
        int ll = cf * 16 + c;
        boff[cf] = (ll * 64 + g * 16) ^ ((ll & 14) << 3);
    }

#define SCHED __builtin_amdgcn_sched_barrier(0)

#define STAGEX(t, bufi) do {                                             \
        char* _d = (char*)xs[bufi] + wv * 4096;                          \
        gload16(pA +     (t) * 128, _d);                                 \
        gload16(pB + 8192  + (t) * 128, _d + 1024);                      \
        gload16(pA + 16384 + (t) * 128, _d + 2048);                      \
        gload16(pB + 24576 + (t) * 128, _d + 3072);                      \
    } while (0)

#define STAGEB(t, bufi) do {                                             \
        gload16(gvs + (t) * 8192, (char*)vs[bufi] + wv * 1024);          \
        gload16(gus + (t) * 8192, (char*)us[bufi] + wv * 1024);          \
    } while (0)

    // prologue: stage step 0 (6 loads per wave)
    STAGEX(0, 0);
    STAGEB(0, 0);
    SCHED;

#pragma unroll
    for (int t = 0; t < 8; ++t) {
        asm volatile("s_waitcnt vmcnt(0)" ::: "memory");  // step-t loads landed
        __builtin_amdgcn_s_barrier();
        SCHED;

        if (t < 7) {
            STAGEX(t + 1, (t + 1) & 1);
            STAGEB(t + 1, (t + 1) & 1);
        }
        SCHED;

        const int buf = t & 1;          // compile-time after unroll
        const char* xbuf = (const char*)xs[buf];
        const char* vbuf = (const char*)vs[buf];
        const char* ubuf = (const char*)us[buf];

        // A-frags: f32 -> bf16 at read time (consumed immediately)
        bf16x8 a0, a1;
        {
            f32x4 p = *(const f32x4*)(xbuf + aoff[0]);
            f32x4 q = *(const f32x4*)(xbuf + (aoff[0] ^ 16));
            a0[0] = (__bf16)p.x; a0[1] = (__bf16)p.y;
            a0[2] = (__bf16)p.z; a0[3] = (__bf16)p.w;
            a0[4] = (__bf16)q.x; a0[5] = (__bf16)q.y;
            a0[6] = (__bf16)q.z; a0[7] = (__bf16)q.w;
            p = *(const f32x4*)(xbuf + aoff[1]);
            q = *(const f32x4*)(xbuf + (aoff[1] ^ 16));
            a1[0] = (__bf16)p.x; a1[1] = (__bf16)p.y;
            a1[2] = (__bf16)p.z; a1[3] = (__bf16)p.w;
            a1[4] = (__bf16)q.x; a1[5] = (__bf16)q.y;
            a1[6] = (__bf16)q.z; a1[7] = (__bf16)q.w;
        }
        __builtin_amdgcn_s_setprio(1);
#pragma unroll
        for (int cf = 0; cf < 4; ++cf) {
            bf16x8 bv = *(const bf16x8*)(vbuf + boff[cf]);
            bf16x8 bu = *(const bf16x8*)(ubuf + boff[cf]);
            accV[0][cf] = __builtin_amdgcn_mfma_f32_16x16x32_bf16(a0, bv, accV[0][cf], 0, 0, 0);
            accV[1][cf] = __builtin_amdgcn_mfma_f32_16x16x32_bf16(a1, bv, accV[1][cf], 0, 0, 0);
            accU[0][cf] = __builtin_amdgcn_mfma_f32_16x16x32_bf16(a0, bu, accU[0][cf], 0, 0, 0);
            accU[1][cf] = __builtin_amdgcn_mfma_f32_16x16x32_bf16(a1, bu, accU[1][cf], 0, 0, 0);
        }
        __builtin_amdgcn_s_setprio(0);
    }
#undef STAGEB
#undef STAGEX
#undef SCHED

    // ---- epilogue: V prescaled 2, U prescaled -1 -> A=e^{2v}, E=e^{-u};
    //      gated=(A-1)/((A+1)(1+E)); dot w over this block's 64 l; 16-lane
    //      shuffle reduce; write PARTIAL logits (summed by softmax).
    const float* wrow = w + h * L_ + lh * 64;
    float* pl = partL + (size_t)lh * (B_ * H_ * N_);
#pragma unroll
    for (int rf = 0; rf < 2; ++rf) {
        float plog[4] = {0.f, 0.f, 0.f, 0.f};
#pragma unroll
        for (int cf = 0; cf < 4; ++cf) {
            float wvv = wrow[cf * 16 + c];
#pragma unroll
            for (int i = 0; i < 4; ++i) {
                float A = __expf(accV[rf][cf][i]);
                float E = __expf(accU[rf][cf][i]);
                float gg = __fdividef(A - 1.f, (A + 1.f) * (1.f + E));
                plog[i] += gg * wvv;
            }
        }
#pragma unroll
        for (int i = 0; i < 4; ++i) {
            float v = plog[i];
            v += __shfl_xor(v, 1);
            v += __shfl_xor(v, 2);
            v += __shfl_xor(v, 4);
            v += __shfl_xor(v, 8);      // sum over the 16 col-lanes
            if (c == 0) {
                int rowflat = tile * 128 + wv * 32 + rf * 16 + g * 4 + i;
                int b = rowflat >> 12;
                int n = rowflat & (N_ - 1);
                pl[((size_t)b * H_ + h) * N_ + n] = v;
            }
        }
    }
}

// ---------------------------------------------------------------------------
// SLOW PATH (round-1 fallback)
// ---------------------------------------------------------------------------
__global__ void prep_vu_slow(const float* __restrict__ V, const float* __restrict__ U,
                             unsigned short* __restrict__ Vt, unsigned short* __restrict__ Ut) {
    int idx = blockIdx.x * 256 + threadIdx.x;
    int m = idx & (M_ - 1);
    int l = (idx >> 8) & (L_ - 1);
    int h = idx >> 15;
    Vt[idx] = f2bf(V[((size_t)h * M_ + m) * L_ + l]);
    Ut[idx] = f2bf(U[((size_t)h * M_ + m) * L_ + l]);
}

#define BM 128
#define BK 64

__global__ __launch_bounds__(256, 2)
void gemm_logits(const float* __restrict__ x,
                 const unsigned short* __restrict__ Vt,
                 const unsigned short* __restrict__ Ut,
                 const float* __restrict__ w,
                 float* __restrict__ logits) {
    __shared__ __align__(16) unsigned short xs[BM * BK];
    __shared__ __align__(16) unsigned short vs[L_ * BK];
    __shared__ __align__(16) unsigned short us[L_ * BK];
    __shared__ float wl[L_];

    const int h    = blockIdx.x >> 10;
    const int tile = blockIdx.x & 1023;
    const int row0 = tile * BM;
    const int tid  = threadIdx.x;
    const int lane = tid & 63;
    const int wave = tid >> 6;

    if (tid < L_) wl[tid] = w[h * L_ + tid];

    f32x4 accV[2][8], accU[2][8];
#pragma unroll
    for (int rf = 0; rf < 2; ++rf)
#pragma unroll
        for (int cf = 0; cf < 8; ++cf) {
            accV[rf][cf] = (f32x4){0.f, 0.f, 0.f, 0.f};
            accU[rf][cf] = (f32x4){0.f, 0.f, 0.f, 0.f};
        }

    const unsigned short* Vh = Vt + (size_t)h * L_ * M_;
    const unsigned short* Uh = Ut + (size_t)h * L_ * M_;
    const int g = lane >> 4;
    const int c = lane & 15;

    for (int ks = 0; ks < 4; ++ks) {
        const int k0 = ks * BK;
        __syncthreads();
#pragma unroll
        for (int p = 0; p < 4; ++p) {
            int row = p * 32 + (tid >> 3);
            int kk  = (tid & 7) * 8;
            const float* gx = x + (size_t)(row0 + row) * M_ + k0 + kk;
            float4 a = *(const float4*)gx;
            float4 b = *(const float4*)(gx + 4);
            uint4 o;
            o.x = pack2(a.x, a.y); o.y = pack2(a.z, a.w);
            o.z = pack2(b.x, b.y); o.w = pack2(b.z, b.w);
            int byte = (row * BK + kk) * 2;
            byte ^= (row & 7) << 4;
            *(uint4*)((char*)xs + byte) = o;
        }
#pragma unroll
        for (int p = 0; p < 4; ++p) {
            int l  = p * 32 + (tid >> 3);
            int kk = (tid & 7) * 8;
            uint4 v = *(const uint4*)(Vh + (size_t)l * M_ + k0 + kk);
            uint4 u = *(const uint4*)(Uh + (size_t)l * M_ + k0 + kk);
            int byte = (l * BK + kk) * 2;
            byte ^= (l & 7) << 4;
            *(uint4*)((char*)vs + byte) = v;
            *(uint4*)((char*)us + byte) = u;
        }
        __syncthreads();
#pragma unroll
        for (int ksub = 0; ksub < 2; ++ksub) {
            bf16x8 afr[2];
#pragma unroll
            for (int rf = 0; rf < 2; ++rf) {
                int row = wave * 32 + rf * 16 + c;
                int byte = (row * BK + ksub * 32 + g * 8) * 2;
                byte ^= (row & 7) << 4;
                afr[rf] = *(const bf16x8*)((const char*)xs + byte);
            }
#pragma unroll
            for (int cf = 0; cf < 8; ++cf) {
                int l = cf * 16 + c;
                int byte = (l * BK + ksub * 32 + g * 8) * 2;
                byte ^= (l & 7) << 4;
                bf16x8 bv = *(const bf16x8*)((const char*)vs + byte);
                bf16x8 bu = *(const bf16x8*)((const char*)us + byte);
#pragma unroll
                for (int rf = 0; rf < 2; ++rf) {
                    accV[rf][cf] = __builtin_amdgcn_mfma_f32_16x16x32_bf16(afr[rf], bv, accV[rf][cf], 0, 0, 0);
                    accU[rf][cf] = __builtin_amdgcn_mfma_f32_16x16x32_bf16(afr[rf], bu, accU[rf][cf], 0, 0, 0);
                }
            }
        }
    }
#pragma unroll
    for (int rf = 0; rf < 2; ++rf) {
        float plog[4] = {0.f, 0.f, 0.f, 0.f};
#pragma unroll
        for (int cf = 0; cf < 8; ++cf) {
            float wvv = wl[cf * 16 + c];
#pragma unroll
            for (int i = 0; i < 4; ++i) {
                float vv = accV[rf][cf][i];
                float uu = accU[rf][cf][i];
                vv = fminf(fmaxf(vv, -20.f), 20.f);
                float e2v = __expf(2.f * vv);
                float t = __fdividef(e2v - 1.f, e2v + 1.f);
                float s = __fdividef(1.f, 1.f + __expf(-uu));
                plog[i] += t * s * wvv;
            }
        }
#pragma unroll
        for (int i = 0; i < 4; ++i) {
            float v = plog[i];
            v += __shfl_xor(v, 1);
            v += __shfl_xor(v, 2);
            v += __shfl_xor(v, 4);
            v += __shfl_xor(v, 8);
            if (c == 0) {
                int rowflat = row0 + wave * 32 + rf * 16 + g * 4 + i;
                int b = rowflat >> 12;
                int n = rowflat & (N_ - 1);
                logits[((size_t)b * H_ + h) * N_ + n] = v;
            }
        }
    }
}

// ---------------------------------------------------------------------------
// softmax^2 from TWO partial-logit halves (fast path): lg = p0 + p1.
// a = e^2/sum(e^2), e = m*exp(m*lg). Writes att in (H,B,N) order.
// ---------------------------------------------------------------------------
__global__ __launch_bounds__(256)
void softmax_att2(const float* __restrict__ pl0, const float* __restrict__ pl1,
                  const float* __restrict__ masks, float* __restrict__ att) {
    const int bh = blockIdx.x;
    const int b = bh >> 2, h = bh & 3;
    __shared__ float e2s[N_];
    __shared__ float red[4];
    const int tid = threadIdx.x;

    float sum = 0.f;
#pragma unroll
    for (int i = 0; i < N_ / 256; ++i) {
        int n = i * 256 + tid;
        size_t idx = ((size_t)b * H_ + h) * N_ + n;
        float lg = pl0[idx] + pl1[idx];
        float mv = masks[(size_t)b * N_ + n];
        float e = mv * __expf(mv * lg);
        float e2 = e * e;
        e2s[n] = e2;
        sum += e2;
    }
#pragma unroll
    for (int off = 32; off >= 1; off >>= 1) sum += __shfl_xor(sum, off);
    if ((tid & 63) == 0) red[tid >> 6] = sum;
    __syncthreads();
    float S = red[0] + red[1] + red[2] + red[3];
    float inv = 1.f / S;
#pragma unroll
    for (int i = 0; i < N_ / 256; ++i) {
        int n = i * 256 + tid;
        att[((size_t)h * B_ + b) * N_ + n] = e2s[n] * inv;
    }
}

// slow-path softmax (single logits buffer)
__global__ __launch_bounds__(256)
void softmax_att(const float* __restrict__ logits, const float* __restrict__ masks,
                 float* __restrict__ att) {
    const int bh = blockIdx.x;
    const int b = bh >> 2, h = bh & 3;
    __shared__ float e2s[N_];
    __shared__ float red[4];
    const int tid = threadIdx.x;

    float sum = 0.f;
#pragma unroll
    for (int i = 0; i < N_ / 256; ++i) {
        int n = i * 256 + tid;
        float lg = logits[((size_t)b * H_ + h) * N_ + n];
        float mv = masks[(size_t)b * N_ + n];
        float e = mv * __expf(mv * lg);
        float e2 = e * e;
        e2s[n] = e2;
        sum += e2;
    }
#pragma unroll
    for (int off = 32; off >= 1; off >>= 1) sum += __shfl_xor(sum, off);
    if ((tid & 63) == 0) red[tid >> 6] = sum;
    __syncthreads();
    float S = red[0] + red[1] + red[2] + red[3];
    float inv = 1.f / S;
#pragma unroll
    for (int i = 0; i < N_ / 256; ++i) {
        int n = i * 256 + tid;
        att[((size_t)h * B_ + b) * N_ + n] = e2s[n] * inv;
    }
}

// ---------------------------------------------------------------------------
// emb: 2-stage deterministic reduction (f32 x for full precision).
// ---------------------------------------------------------------------------
#define NCH 32
#define CHUNK (N_ / NCH)   // 128

__global__ __launch_bounds__(256)
void emb_partial(const float* __restrict__ x, const float* __restrict__ att,
                 float* __restrict__ part) {
    const int bc = blockIdx.x;
    const int b = bc >> 5, ch = bc & 31;
    __shared__ float as[H_][CHUNK];
    const int tid = threadIdx.x;

    for (int i = tid; i < H_ * CHUNK; i += 256) {
        int hh = i >> 7;
        int j  = i & (CHUNK - 1);
        as[hh][j] = att[((size_t)hh * B_ + b) * N_ + ch * CHUNK + j];
    }
    __syncthreads();

    float a0 = 0.f, a1 = 0.f, a2 = 0.f, a3 = 0.f;
    const float* xp = x + ((size_t)b * N_ + ch * CHUNK) * M_ + tid;
#pragma unroll 4
    for (int j = 0; j < CHUNK; ++j) {
        float xv = xp[(size_t)j * M_];
        a0 += as[0][j] * xv;
        a1 += as[1][j] * xv;
        a2 += as[2][j] * xv;
        a3 += as[3][j] * xv;
    }
    float* pp = part + (size_t)bc * H_ * M_ + tid;
    pp[0 * M_] = a0; pp[1 * M_] = a1; pp[2 * M_] = a2; pp[3 * M_] = a3;
}

__global__ __launch_bounds__(256)
void emb_reduce(const float* __restrict__ part, float* __restrict__ emb) {
    int idx = blockIdx.x * 256 + threadIdx.x;
    int b = idx >> 10;
    int r = idx & 1023;
    float s = 0.f;
#pragma unroll
    for (int ci = 0; ci < NCH; ++ci)
        s += part[((size_t)(b * NCH + ci)) * (H_ * M_) + r];
    emb[idx] = s;
}

// ---------------------------------------------------------------------------
extern "C" void kernel_launch(void* const* d_in, const int* in_sizes, int n_in,
                              void* d_out, int out_size, void* d_ws, size_t ws_size,
                              hipStream_t stream) {
    const float* x     = (const float*)d_in[0];
    const float* masks = (const float*)d_in[1];
    const float* V     = (const float*)d_in[2];
    const float* U     = (const float*)d_in[3];
    const float* w     = (const float*)d_in[4];

    float* att = (float*)d_out;                       // (H,B,N,1)
    float* emb = att + (size_t)H_ * B_ * N_;          // (B,H*M)

    char* ws = (char*)d_ws;
    const size_t VU_BYTES  = (size_t)128 * 4096;              // 524,288
    const size_t PL_BYTES  = (size_t)2 * B_ * H_ * N_ * 4;    // 4,194,304
    const size_t PT_BYTES  = (size_t)B_ * NCH * H_ * M_ * 4;  // 4,194,304
    const size_t NEED_FAST = VU_BYTES + PL_BYTES + PT_BYTES;

    if (ws_size >= NEED_FAST) {
        unsigned short* vuimg = (unsigned short*)ws;
        float* partL = (float*)(ws + VU_BYTES);
        float* partp = (float*)(ws + VU_BYTES + PL_BYTES);

        prep_vu_img2<<<32,   256, 0, stream>>>(V, U, vuimg);
        gemm_fast10 <<<8192, 256, 0, stream>>>(x, vuimg, w, partL);
        softmax_att2<<<B_ * H_, 256, 0, stream>>>(partL,
                                                  partL + (size_t)B_ * H_ * N_,
                                                  masks, att);
        emb_partial<<<B_ * NCH, 256, 0, stream>>>(x, att, partp);
        emb_reduce <<<(B_ * H_ * M_) / 256, 256, 0, stream>>>(partp, emb);
    } else {
        unsigned short* Vt = (unsigned short*)ws;
        unsigned short* Ut = (unsigned short*)(ws + 262144);
        float* logits = (float*)(ws + 524288);
        float* partp  = (float*)(ws + 524288 + (size_t)B_ * H_ * N_ * 4);

        prep_vu_slow<<<512, 256, 0, stream>>>(V, U, Vt, Ut);
        gemm_logits <<<4096, 256, 0, stream>>>(x, Vt, Ut, w, logits);
        softmax_att <<<B_ * H_, 256, 0, stream>>>(logits, masks, att);
        emb_partial <<<B_ * NCH, 256, 0, stream>>>(x, att, partp);
        emb_reduce  <<<(B_ * H_ * M_) / 256, 256, 0, stream>>>(partp, emb);
    }
}

// Round 12
// 151.473 us; speedup vs baseline: 1.4514x; 1.0557x over previous
//
#include <hip/hip_runtime.h>
#include <hip/hip_bf16.h>
#include <stdint.h>

// Problem constants
#define B_ 32
#define N_ 4096
#define M_ 256
#define L_ 128
#define H_ 4
#define BN_ (B_ * N_)          // 131072 flattened rows

typedef __bf16 bf16x8 __attribute__((ext_vector_type(8)));
typedef float  f32x4  __attribute__((ext_vector_type(4)));

__device__ __forceinline__ unsigned short f2bf(float f) {
    unsigned int u = __float_as_uint(f);
    u += 0x7fffu + ((u >> 16) & 1u);
    return (unsigned short)(u >> 16);
}
__device__ __forceinline__ unsigned int pack2(float lo, float hi) {
    return (unsigned int)f2bf(lo) | ((unsigned int)f2bf(hi) << 16);
}

// async global->LDS, 16B/lane; LDS dest wave-uniform base + lane*16 (HW);
// global src per-lane (m173: pre-permute SOURCE to realize a swizzled layout).
__device__ __forceinline__ void gload16(const void* g, void* l) {
    __builtin_amdgcn_global_load_lds(
        (const __attribute__((address_space(1))) unsigned int*)g,
        (__attribute__((address_space(3))) unsigned int*)l, 16, 0, 0);
}

// ---------------------------------------------------------------------------
// prep: V,U (H,M,L) f32 -> vu2 4KB images [(((h*2+lh)*8 + s)*2 + mat)]
// [64 l][32 m] bf16, swizzle byte ^= (ll&14)<<3, PRESCALED (V*=2, U*=-1).
// ---------------------------------------------------------------------------
__global__ void prep_vu_img2(const float* __restrict__ V, const float* __restrict__ U,
                             unsigned short* __restrict__ vu) {
    __shared__ float slab[64][129];     // [m][l], padded
    const int b   = blockIdx.x;         // 32 = h(4) * ks64(4) * mat(2)
    const int mat = b & 1, ks = (b >> 1) & 3, h = b >> 3;
    const float* src = (mat ? U : V) + ((size_t)h * M_ + ks * 64) * L_;
    const float scale = mat ? -1.0f : 2.0f;
    const int tid = threadIdx.x;
#pragma unroll
    for (int rep = 0; rep < 32; ++rep) {
        int idx = rep * 256 + tid;      // 8192 = 64m x 128l
        slab[idx >> 7][idx & 127] = scale * src[(size_t)(idx >> 7) * L_ + (idx & 127)];
    }
    __syncthreads();
#pragma unroll
    for (int rep = 0; rep < 4; ++rep) {
        int cidx = rep * 256 + tid;     // 1024 chunks of 16B
        int l  = cidx >> 3;             // 0..127
        int kk = (cidx & 7) * 8;        // 0..56
        uint4 o;
        o.x = pack2(slab[kk + 0][l], slab[kk + 1][l]);
        o.y = pack2(slab[kk + 2][l], slab[kk + 3][l]);
        o.z = pack2(slab[kk + 4][l], slab[kk + 5][l]);
        o.w = pack2(slab[kk + 6][l], slab[kk + 7][l]);
        int tl = kk >> 5, kl = kk & 31;
        int lh = l >> 6, ll = l & 63;
        char* dst = (char*)vu
            + ((((size_t)(h * 2 + lh) * 8 + (ks * 2 + tl)) * 2) + mat) * 4096;
        int byte = (ll * 64 + kl * 2) ^ ((ll & 14) << 3);
        *(uint4*)(dst + byte) = o;
    }
}

// ---------------------------------------------------------------------------
// gemm_fast11: r11 structure with x SINGLE-buffered (LDS 48->32KB) for
// 4-5 blocks/CU (~50%+ occupancy). Two barriers per step:
//   [vmcnt(0): x(t)+B(t) landed][barrier1]
//   [read A-frags (4x ds_read_b128 f32) + cvt->bf16 regs][lgkmcnt(0)][barrier2]
//   [stage x(t+1) into SAME xs (safe: all x reads done) + B(t+1) dbuf]
//   [32 MFMA; B-frags ds_read'd from stable dbuf inside the loop]
// Block = 128 rows x 64 l x {V,U} for one (tile,h,lh); acc = 64 VGPR;
// writes PARTIAL logits (softmax sums the two l-halves).
// ---------------------------------------------------------------------------
__global__ __launch_bounds__(256, 4)
void gemm_fast11(const float* __restrict__ x,
                 const unsigned short* __restrict__ vu,
                 const float* __restrict__ w,
                 float* __restrict__ partL) {
    __shared__ __align__(16) float          xs[4096];      // 16KB, single buffer
    __shared__ __align__(16) unsigned short vs[2][2048];   // 2 x 4KB
    __shared__ __align__(16) unsigned short us[2][2048];   // 2 x 4KB

    const int orig    = blockIdx.x;                 // 8192, %8==0 -> bijective
    const int logical = (orig & 7) * 1024 + (orig >> 3);
    const int tile    = logical >> 3;
    const int h       = (logical >> 1) & 3;
    const int lh      = logical & 1;

    const int tid  = threadIdx.x;
    const int lane = tid & 63;
    const int wv   = tid >> 6;
    const int g    = lane >> 4;     // k-group 0..3
    const int c    = lane & 15;     // row (A) / col (B) within fragment

    f32x4 accV[2][4], accU[2][4];   // 64 VGPR total
#pragma unroll
    for (int rf = 0; rf < 2; ++rf)
#pragma unroll
        for (int cf = 0; cf < 4; ++cf) {
            accV[rf][cf] = (f32x4){0.f, 0.f, 0.f, 0.f};
            accU[rf][cf] = (f32x4){0.f, 0.f, 0.f, 0.f};
        }

    // ---- B global sources: 4KB images, step stride 8192B (v+u) ----
    const char* gvs = (const char*)vu + (size_t)(h * 2 + lh) * 65536
                      + wv * 1024 + lane * 16;
    const char* gus = gvs + 4096;

    // ---- x staging source (inverse-swizzled per-lane addresses) ----
    // dest s = wv*4096 + j*1024 + lane*16 -> row = wv*32 + j*8 + (lane>>3),
    // off = (lane&7)*16 ^ ((row&14)<<3); bits4-5 from lane>>3, bit6 from j&1.
    const int offb = ((lane & 7) << 4) ^ (((lane >> 3) & 6) << 3);
    const char* pA = (const char*)x
        + ((size_t)tile * 128 + wv * 32 + (lane >> 3)) * 1024 + offb;        // j even
    const char* pB = (const char*)x
        + ((size_t)tile * 128 + wv * 32 + (lane >> 3)) * 1024 + (offb ^ 64); // j odd

    // ---- LDS read offsets ----
    int aoff[2], boff[4];
#pragma unroll
    for (int rf = 0; rf < 2; ++rf) {
        int r = wv * 32 + rf * 16 + c;
        aoff[rf] = (r * 128 + g * 32) ^ ((c & 14) << 3);
    }
#pragma unroll
    for (int cf = 0; cf < 4; ++cf) {
        int ll = cf * 16 + c;
        boff[cf] = (ll * 64 + g * 16) ^ ((ll & 14) << 3);
    }

#define SCHED __builtin_amdgcn_sched_barrier(0)

#define STAGEX(t) do {                                                   \
        char* _d = (char*)xs + wv * 4096;                                \
        gload16(pA +         (t) * 128, _d);                             \
        gload16(pB + 8192  + (t) * 128, _d + 1024);                      \
        gload16(pA + 16384 + (t) * 128, _d + 2048);                      \
        gload16(pB + 24576 + (t) * 128, _d + 3072);                      \
    } while (0)

#define STAGEB(t, bufi) do {                                             \
        gload16(gvs + (t) * 8192, (char*)vs[bufi] + wv * 1024);          \
        gload16(gus + (t) * 8192, (char*)us[bufi] + wv * 1024);          \
    } while (0)

    // prologue: stage step 0 (6 loads per wave)
    STAGEX(0);
    STAGEB(0, 0);
    SCHED;

#pragma unroll
    for (int t = 0; t < 8; ++t) {
        asm volatile("s_waitcnt vmcnt(0)" ::: "memory");  // x(t)+B(t) landed
        __builtin_amdgcn_s_barrier();                     // barrier 1
        SCHED;

        // ---- A-frags: f32 LDS -> regs -> bf16 (before xs is recycled) ----
        bf16x8 a0, a1;
        {
            f32x4 p = *(const f32x4*)((const char*)xs + aoff[0]);
            f32x4 q = *(const f32x4*)((const char*)xs + (aoff[0] ^ 16));
            a0[0] = (__bf16)p.x; a0[1] = (__bf16)p.y;
            a0[2] = (__bf16)p.z; a0[3] = (__bf16)p.w;
            a0[4] = (__bf16)q.x; a0[5] = (__bf16)q.y;
            a0[6] = (__bf16)q.z; a0[7] = (__bf16)q.w;
            p = *(const f32x4*)((const char*)xs + aoff[1]);
            q = *(const f32x4*)((const char*)xs + (aoff[1] ^ 16));
            a1[0] = (__bf16)p.x; a1[1] = (__bf16)p.y;
            a1[2] = (__bf16)p.z; a1[3] = (__bf16)p.w;
            a1[4] = (__bf16)q.x; a1[5] = (__bf16)q.y;
            a1[6] = (__bf16)q.z; a1[7] = (__bf16)q.w;
        }

        if (t < 7) {
            asm volatile("s_waitcnt lgkmcnt(0)" ::: "memory");
            SCHED;
            __builtin_amdgcn_s_barrier();                 // barrier 2: xs free
            SCHED;
            STAGEX(t + 1);                                // same buffer, now safe
            STAGEB(t + 1, (t + 1) & 1);
            SCHED;
        }

        const int buf = t & 1;          // compile-time after unroll
        const char* vbuf = (const char*)vs[buf];
        const char* ubuf = (const char*)us[buf];

        __builtin_amdgcn_s_setprio(1);
#pragma unroll
        for (int cf = 0; cf < 4; ++cf) {
            bf16x8 bv = *(const bf16x8*)(vbuf + boff[cf]);
            bf16x8 bu = *(const bf16x8*)(ubuf + boff[cf]);
            accV[0][cf] = __builtin_amdgcn_mfma_f32_16x16x32_bf16(a0, bv, accV[0][cf], 0, 0, 0);
            accV[1][cf] = __builtin_amdgcn_mfma_f32_16x16x32_bf16(a1, bv, accV[1][cf], 0, 0, 0);
            accU[0][cf] = __builtin_amdgcn_mfma_f32_16x16x32_bf16(a0, bu, accU[0][cf], 0, 0, 0);
            accU[1][cf] = __builtin_amdgcn_mfma_f32_16x16x32_bf16(a1, bu, accU[1][cf], 0, 0, 0);
        }
        __builtin_amdgcn_s_setprio(0);
    }
#undef STAGEB
#undef STAGEX
#undef SCHED

    // ---- epilogue: V prescaled 2, U prescaled -1 -> A=e^{2v}, E=e^{-u};
    //      gated=(A-1)/((A+1)(1+E)); dot w over this block's 64 l; 16-lane
    //      shuffle reduce; write PARTIAL logits (summed by softmax).
    const float* wrow = w + h * L_ + lh * 64;
    float* pl = partL + (size_t)lh * (B_ * H_ * N_);
#pragma unroll
    for (int rf = 0; rf < 2; ++rf) {
        float plog[4] = {0.f, 0.f, 0.f, 0.f};
#pragma unroll
        for (int cf = 0; cf < 4; ++cf) {
            float wvv = wrow[cf * 16 + c];
#pragma unroll
            for (int i = 0; i < 4; ++i) {
                float A = __expf(accV[rf][cf][i]);
                float E = __expf(accU[rf][cf][i]);
                float gg = __fdividef(A - 1.f, (A + 1.f) * (1.f + E));
                plog[i] += gg * wvv;
            }
        }
#pragma unroll
        for (int i = 0; i < 4; ++i) {
            float v = plog[i];
            v += __shfl_xor(v, 1);
            v += __shfl_xor(v, 2);
            v += __shfl_xor(v, 4);
            v += __shfl_xor(v, 8);      // sum over the 16 col-lanes
            if (c == 0) {
                int rowflat = tile * 128 + wv * 32 + rf * 16 + g * 4 + i;
                int b = rowflat >> 12;
                int n = rowflat & (N_ - 1);
                pl[((size_t)b * H_ + h) * N_ + n] = v;
            }
        }
    }
}

// ---------------------------------------------------------------------------
// SLOW PATH (round-1 fallback)
// ---------------------------------------------------------------------------
__global__ void prep_vu_slow(const float* __restrict__ V, const float* __restrict__ U,
                             unsigned short* __restrict__ Vt, unsigned short* __restrict__ Ut) {
    int idx = blockIdx.x * 256 + threadIdx.x;
    int m = idx & (M_ - 1);
    int l = (idx >> 8) & (L_ - 1);
    int h = idx >> 15;
    Vt[idx] = f2bf(V[((size_t)h * M_ + m) * L_ + l]);
    Ut[idx] = f2bf(U[((size_t)h * M_ + m) * L_ + l]);
}

#define BM 128
#define BK 64

__global__ __launch_bounds__(256, 2)
void gemm_logits(const float* __restrict__ x,
                 const unsigned short* __restrict__ Vt,
                 const unsigned short* __restrict__ Ut,
                 const float* __restrict__ w,
                 float* __restrict__ logits) {
    __shared__ __align__(16) unsigned short xs[BM * BK];
    __shared__ __align__(16) unsigned short vs[L_ * BK];
    __shared__ __align__(16) unsigned short us[L_ * BK];
    __shared__ float wl[L_];

    const int h    = blockIdx.x >> 10;
    const int tile = blockIdx.x & 1023;
    const int row0 = tile * BM;
    const int tid  = threadIdx.x;
    const int lane = tid & 63;
    const int wave = tid >> 6;

    if (tid < L_) wl[tid] = w[h * L_ + tid];

    f32x4 accV[2][8], accU[2][8];
#pragma unroll
    for (int rf = 0; rf < 2; ++rf)
#pragma unroll
        for (int cf = 0; cf < 8; ++cf) {
            accV[rf][cf] = (f32x4){0.f, 0.f, 0.f, 0.f};
            accU[rf][cf] = (f32x4){0.f, 0.f, 0.f, 0.f};
        }

    const unsigned short* Vh = Vt + (size_t)h * L_ * M_;
    const unsigned short* Uh = Ut + (size_t)h * L_ * M_;
    const int g = lane >> 4;
    const int c = lane & 15;

    for (int ks = 0; ks < 4; ++ks) {
        const int k0 = ks * BK;
        __syncthreads();
#pragma unroll
        for (int p = 0; p < 4; ++p) {
            int row = p * 32 + (tid >> 3);
            int kk  = (tid & 7) * 8;
            const float* gx = x + (size_t)(row0 + row) * M_ + k0 + kk;
            float4 a = *(const float4*)gx;
            float4 b = *(const float4*)(gx + 4);
            uint4 o;
            o.x = pack2(a.x, a.y); o.y = pack2(a.z, a.w);
            o.z = pack2(b.x, b.y); o.w = pack2(b.z, b.w);
            int byte = (row * BK + kk) * 2;
            byte ^= (row & 7) << 4;
            *(uint4*)((char*)xs + byte) = o;
        }
#pragma unroll
        for (int p = 0; p < 4; ++p) {
            int l  = p * 32 + (tid >> 3);
            int kk = (tid & 7) * 8;
            uint4 v = *(const uint4*)(Vh + (size_t)l * M_ + k0 + kk);
            uint4 u = *(const uint4*)(Uh + (size_t)l * M_ + k0 + kk);
            int byte = (l * BK + kk) * 2;
            byte ^= (l & 7) << 4;
            *(uint4*)((char*)vs + byte) = v;
            *(uint4*)((char*)us + byte) = u;
        }
        __syncthreads();
#pragma unroll
        for (int ksub = 0; ksub < 2; ++ksub) {
            bf16x8 afr[2];
#pragma unroll
            for (int rf = 0; rf < 2; ++rf) {
                int row = wave * 32 + rf * 16 + c;
                int byte = (row * BK + ksub * 32 + g * 8) * 2;
                byte ^= (row & 7) << 4;
                afr[rf] = *(const bf16x8*)((const char*)xs + byte);
            }
#pragma unroll
            for (int cf = 0; cf < 8; ++cf) {
                int l = cf * 16 + c;
                int byte = (l * BK + ksub * 32 + g * 8) * 2;
                byte ^= (l & 7) << 4;
                bf16x8 bv = *(const bf16x8*)((const char*)vs + byte);
                bf16x8 bu = *(const bf16x8*)((const char*)us + byte);
#pragma unroll
                for (int rf = 0; rf < 2; ++rf) {
                    accV[rf][cf] = __builtin_amdgcn_mfma_f32_16x16x32_bf16(afr[rf], bv, accV[rf][cf], 0, 0, 0);
                    accU[rf][cf] = __builtin_amdgcn_mfma_f32_16x16x32_bf16(afr[rf], bu, accU[rf][cf], 0, 0, 0);
                }
            }
        }
    }
#pragma unroll
    for (int rf = 0; rf < 2; ++rf) {
        float plog[4] = {0.f, 0.f, 0.f, 0.f};
#pragma unroll
        for (int cf = 0; cf < 8; ++cf) {
            float wvv = wl[cf * 16 + c];
#pragma unroll
            for (int i = 0; i < 4; ++i) {
                float vv = accV[rf][cf][i];
                float uu = accU[rf][cf][i];
                vv = fminf(fmaxf(vv, -20.f), 20.f);
                float e2v = __expf(2.f * vv);
                float t = __fdividef(e2v - 1.f, e2v + 1.f);
                float s = __fdividef(1.f, 1.f + __expf(-uu));
                plog[i] += t * s * wvv;
            }
        }
#pragma unroll
        for (int i = 0; i < 4; ++i) {
            float v = plog[i];
            v += __shfl_xor(v, 1);
            v += __shfl_xor(v, 2);
            v += __shfl_xor(v, 4);
            v += __shfl_xor(v, 8);
            if (c == 0) {
                int rowflat = row0 + wave * 32 + rf * 16 + g * 4 + i;
                int b = rowflat >> 12;
                int n = rowflat & (N_ - 1);
                logits[((size_t)b * H_ + h) * N_ + n] = v;
            }
        }
    }
}

// ---------------------------------------------------------------------------
// softmax^2 from TWO partial-logit halves (fast path): lg = p0 + p1.
// a = e^2/sum(e^2), e = m*exp(m*lg). Writes att in (H,B,N) order.
// ---------------------------------------------------------------------------
__global__ __launch_bounds__(256)
void softmax_att2(const float* __restrict__ pl0, const float* __restrict__ pl1,
                  const float* __restrict__ masks, float* __restrict__ att) {
    const int bh = blockIdx.x;
    const int b = bh >> 2, h = bh & 3;
    __shared__ float e2s[N_];
    __shared__ float red[4];
    const int tid = threadIdx.x;

    float sum = 0.f;
#pragma unroll
    for (int i = 0; i < N_ / 256; ++i) {
        int n = i * 256 + tid;
        size_t idx = ((size_t)b * H_ + h) * N_ + n;
        float lg = pl0[idx] + pl1[idx];
        float mv = masks[(size_t)b * N_ + n];
        float e = mv * __expf(mv * lg);
        float e2 = e * e;
        e2s[n] = e2;
        sum += e2;
    }
#pragma unroll
    for (int off = 32; off >= 1; off >>= 1) sum += __shfl_xor(sum, off);
    if ((tid & 63) == 0) red[tid >> 6] = sum;
    __syncthreads();
    float S = red[0] + red[1] + red[2] + red[3];
    float inv = 1.f / S;
#pragma unroll
    for (int i = 0; i < N_ / 256; ++i) {
        int n = i * 256 + tid;
        att[((size_t)h * B_ + b) * N_ + n] = e2s[n] * inv;
    }
}

// slow-path softmax (single logits buffer)
__global__ __launch_bounds__(256)
void softmax_att(const float* __restrict__ logits, const float* __restrict__ masks,
                 float* __restrict__ att) {
    const int bh = blockIdx.x;
    const int b = bh >> 2, h = bh & 3;
    __shared__ float e2s[N_];
    __shared__ float red[4];
    const int tid = threadIdx.x;

    float sum = 0.f;
#pragma unroll
    for (int i = 0; i < N_ / 256; ++i) {
        int n = i * 256 + tid;
        float lg = logits[((size_t)b * H_ + h) * N_ + n];
        float mv = masks[(size_t)b * N_ + n];
        float e = mv * __expf(mv * lg);
        float e2 = e * e;
        e2s[n] = e2;
        sum += e2;
    }
#pragma unroll
    for (int off = 32; off >= 1; off >>= 1) sum += __shfl_xor(sum, off);
    if ((tid & 63) == 0) red[tid >> 6] = sum;
    __syncthreads();
    float S = red[0] + red[1] + red[2] + red[3];
    float inv = 1.f / S;
#pragma unroll
    for (int i = 0; i < N_ / 256; ++i) {
        int n = i * 256 + tid;
        att[((size_t)h * B_ + b) * N_ + n] = e2s[n] * inv;
    }
}

// ---------------------------------------------------------------------------
// emb: 2-stage deterministic reduction (f32 x for full precision).
// ---------------------------------------------------------------------------
#define NCH 32
#define CHUNK (N_ / NCH)   // 128

__global__ __launch_bounds__(256)
void emb_partial(const float* __restrict__ x, const float* __restrict__ att,
                 float* __restrict__ part) {
    const int bc = blockIdx.x;
    const int b = bc >> 5, ch = bc & 31;
    __shared__ float as[H_][CHUNK];
    const int tid = threadIdx.x;

    for (int i = tid; i < H_ * CHUNK; i += 256) {
        int hh = i >> 7;
        int j  = i & (CHUNK - 1);
        as[hh][j] = att[((size_t)hh * B_ + b) * N_ + ch * CHUNK + j];
    }
    __syncthreads();

    float a0 = 0.f, a1 = 0.f, a2 = 0.f, a3 = 0.f;
    const float* xp = x + ((size_t)b * N_ + ch * CHUNK) * M_ + tid;
#pragma unroll 4
    for (int j = 0; j < CHUNK; ++j) {
        float xv = xp[(size_t)j * M_];
        a0 += as[0][j] * xv;
        a1 += as[1][j] * xv;
        a2 += as[2][j] * xv;
        a3 += as[3][j] * xv;
    }
    float* pp = part + (size_t)bc * H_ * M_ + tid;
    pp[0 * M_] = a0; pp[1 * M_] = a1; pp[2 * M_] = a2; pp[3 * M_] = a3;
}

__global__ __launch_bounds__(256)
void emb_reduce(const float* __restrict__ part, float* __restrict__ emb) {
    int idx = blockIdx.x * 256 + threadIdx.x;
    int b = idx >> 10;
    int r = idx & 1023;
    float s = 0.f;
#pragma unroll
    for (int ci = 0; ci < NCH; ++ci)
        s += part[((size_t)(b * NCH + ci)) * (H_ * M_) + r];
    emb[idx] = s;
}

// ---------------------------------------------------------------------------
extern "C" void kernel_launch(void* const* d_in, const int* in_sizes, int n_in,
                              void* d_out, int out_size, void* d_ws, size_t ws_size,
                              hipStream_t stream) {
    const float* x     = (const float*)d_in[0];
    const float* masks = (const float*)d_in[1];
    const float* V     = (const float*)d_in[2];
    const float* U     = (const float*)d_in[3];
    const float* w     = (const float*)d_in[4];

    float* att = (float*)d_out;                       // (H,B,N,1)
    float* emb = att + (size_t)H_ * B_ * N_;          // (B,H*M)

    char* ws = (char*)d_ws;
    const size_t VU_BYTES  = (size_t)128 * 4096;              // 524,288
    const size_t PL_BYTES  = (size_t)2 * B_ * H_ * N_ * 4;    // 4,194,304
    const size_t PT_BYTES  = (size_t)B_ * NCH * H_ * M_ * 4;  // 4,194,304
    const size_t NEED_FAST = VU_BYTES + PL_BYTES + PT_BYTES;

    if (ws_size >= NEED_FAST) {
        unsigned short* vuimg = (unsigned short*)ws;
        float* partL = (float*)(ws + VU_BYTES);
        float* partp = (float*)(ws + VU_BYTES + PL_BYTES);

        prep_vu_img2<<<32,   256, 0, stream>>>(V, U, vuimg);
        gemm_fast11 <<<8192, 256, 0, stream>>>(x, vuimg, w, partL);
        softmax_att2<<<B_ * H_, 256, 0, stream>>>(partL,
                                                  partL + (size_t)B_ * H_ * N_,
                                                  masks, att);
        emb_partial<<<B_ * NCH, 256, 0, stream>>>(x, att, partp);
        emb_reduce <<<(B_ * H_ * M_) / 256, 256, 0, stream>>>(partp, emb);
    } else {
        unsigned short* Vt = (unsigned short*)ws;
        unsigned short* Ut = (unsigned short*)(ws + 262144);
        float* logits = (float*)(ws + 524288);
        float* partp  = (float*)(ws + 524288 + (size_t)B_ * H_ * N_ * 4);

        prep_vu_slow<<<512, 256, 0, stream>>>(V, U, Vt, Ut);
        gemm_logits <<<4096, 256, 0, stream>>>(x, Vt, Ut, w, logits);
        softmax_att <<<B_ * H_, 256, 0, stream>>>(logits, masks, att);
        emb_partial <<<B_ * NCH, 256, 0, stream>>>(x, att, partp);
        emb_reduce  <<<(B_ * H_ * M_) / 256, 256, 0, stream>>>(partp, emb);
    }
}